// Round 9
// baseline (123.783 us; speedup 1.0000x reference)
//
#include <hip/hip_runtime.h>
#include <math.h>

#define B_TOT 8192
#define L_HIST 512
#define HF 64
// 8 lanes per element, 4 neurons per lane -> 1024 waves = 1 per SIMD

typedef __attribute__((ext_vector_type(2))) float f2;

__device__ __forceinline__ f2 bc(float x) { f2 r; r.x = x; r.y = x; return r; }
__device__ __forceinline__ f2 fma2(f2 a, f2 b, f2 c) {
    return __builtin_elementwise_fma(a, b, c);
}

struct Consts {
    f2 expc;              // {-alpha, -1/tau_n}
    float kappa, c, vc2, qxs, qus, qn, Rw, b28;   // b28 = b2/8
};
struct Wgt {              // per-lane 4 neurons as 2 packed pairs
    f2 wu0, wu1, wv0, wv1, wd0, wd1, wb0, wb1, wn0, wn1;
};
struct KS { float x, u, n, p00, p01, p02, p11, p12, p22; };
struct Pre {              // state-independent per-step precompute
    f2 pre0, pre1;        // W1v*v + W1d*dv + b1 (packed pairs)
    float dt, rho, phi, a, cgdt, qxdt, qudt, dtb28;  // dtb28 = dt*b2/8
};

// DPP 8-lane group sum: xor1, xor2 (quad_perm), xor4 (row_half_mirror).
template<int CTRL>
__device__ __forceinline__ float dpp_add(float x) {
    int y = __builtin_amdgcn_update_dpp(__float_as_int(x), __float_as_int(x),
                                        CTRL, 0xF, 0xF, false);
    return x + __int_as_float(y);
}
__device__ __forceinline__ float gsum8(float x) {
    x = dpp_add<0xB1>(x);
    x = dpp_add<0x4E>(x);
    x = dpp_add<0x141>(x);
    return x;
}

__device__ __forceinline__ Pre mkpre(const Consts& C, const Wgt& w,
                                     float dt, float v_c, float dv) {
    Pre p;
    p.dt = dt;
    // rho = exp(-alpha dt), phi = exp(-dt/tau): 4th-order Taylor (|z|<=0.2).
    f2 z = C.expc * bc(dt);
    f2 e = fma2(fma2(fma2(fma2(z, bc(0.041666668f), bc(0.16666667f)),
                          z, bc(0.5f)), z, bc(1.0f)), z, bc(1.0f));
    p.rho = e.x; p.phi = e.y;
    p.a = -C.kappa * dt;
    float g = fmaxf(fmaf(v_c, v_c, -C.vc2), 0.f);
    p.cgdt = (C.c * g) * dt;
    p.qxdt = C.qxs * dt;
    p.qudt = C.qus * dt;
    p.dtb28 = C.b28 * dt;
    f2 vv = bc(v_c), dd = bc(dv);
    p.pre0 = fma2(vv, w.wv0, fma2(dd, w.wd0, w.wb0));
    p.pre1 = fma2(vv, w.wv1, fma2(dd, w.wd1, w.wb1));
    return p;
}

template<bool UPD>
__device__ __forceinline__ void kcore(const Consts& C, const Wgt& w,
                                      const Pre& p, float obs, KS& s) {
    // ---- MLP chain: t -> Pade-5/4, COMMON-DENOMINATOR sum (1 rcp, short tail)
    // sum_j wn_j*h_j/d_j = [PB*(hw0x*d0y+hw0y*d0x)+PA*(hw1x*d1y+hw1y*d1x)]/(PA*PB)
    // num tree overlaps the rcp latency; d >= 945 always (no cancellation).
    f2 uu = bc(s.u);
    f2 t0 = fma2(uu, w.wu0, p.pre0);
    f2 t1 = fma2(uu, w.wu1, p.pre1);
    f2 tw0 = t0 * w.wn0;               // wn folded early, parallel with s
    f2 tw1 = t1 * w.wn1;
    f2 s0 = t0 * t0, s1 = t1 * t1;
    f2 hw0 = fma2(s0 + bc(105.f), s0, bc(945.f)) * tw0;   // wn*t*(s^2+105s+945)
    f2 hw1 = fma2(s1 + bc(105.f), s1, bc(945.f)) * tw1;
    f2 d0 = fma2(fma2(bc(15.f), s0, bc(420.f)), s0, bc(945.f));
    f2 d1 = fma2(fma2(bc(15.f), s1, bc(420.f)), s1, bc(945.f));
    float PA = d0.x * d0.y, PB = d1.x * d1.y;
    float rD = __builtin_amdgcn_rcpf(PA * PB);
    float n0 = fmaf(hw0.y, d0.x, hw0.x * d0.y);
    float n1 = fmaf(hw1.y, d1.x, hw1.x * d1.y);
    float num = fmaf(PA, n1, PB * n0);
    float cl_s = num * rD;             // per-lane sum of 4 wn*tanh fractions

    // ---- cl-independent: state/covariance predict + gain (fills the shadow) ----
    float x_p = fmaf(s.u, p.dt, s.x);
    float n_p = p.phi * s.n;
    float E = fmaf(p.a, s.x, fmaf(p.rho, s.u, p.cgdt));  // u_p = E + dt*cl

    float t0c = fmaf(p.dt, s.p01, s.p00);
    float t1c = fmaf(p.dt, s.p11, s.p01);
    float t2c = fmaf(p.dt, s.p12, s.p02);
    float np00 = fmaf(p.dt, t1c, t0c) + p.qxdt;
    float np01 = fmaf(p.a, t0c, p.rho * t1c);
    float np02 = p.phi * t2c;
    float u0c = fmaf(p.a, s.p00, p.rho * s.p01);
    float u1c = fmaf(p.a, s.p01, p.rho * s.p11);
    float u2c = fmaf(p.a, s.p02, p.rho * s.p12);
    float np11 = fmaf(p.a, u0c, p.rho * u1c) + p.qudt;
    float np12 = p.phi * u2c;
    float np22 = fmaf(p.phi * p.phi, s.p22, C.qn);

    if (UPD) {
        float innov = obs - (x_p + n_p);
        float r0k = np00 + np02;
        float r1k = np01 + np12;
        float r2k = np02 + np22;
        float S  = r0k + r2k + C.Rw;
        float rS = __builtin_amdgcn_rcpf(S);
        float k0 = r0k * rS, k1 = r1k * rS, k2 = r2k * rS;
        s.x = fmaf(k0, innov, x_p);
        s.n = fmaf(k2, innov, n_p);
        // simple-form update (== Joseph for optimal K): P = P_pred - K r^T
        s.p00 = fmaf(-k0, r0k, np00);
        s.p01 = fmaf(-k0, r1k, np01);
        s.p02 = fmaf(-k0, r2k, np02);
        s.p11 = fmaf(-k1, r1k, np11);
        s.p12 = fmaf(-k1, r2k, np12);
        s.p22 = fmaf(-k2, r2k, np22);
        // zero post-reduce tail: u = gsum8(dt*cl_s + (G + dt*b2)/8)
        float G = fmaf(k1, innov, E);
        float seed = fmaf(0.125f, G, p.dtb28);
        s.u = gsum8(fmaf(p.dt, cl_s, seed));
    } else {
        s.x = x_p; s.n = n_p;
        float seed = fmaf(0.125f, E, p.dtb28);
        s.u = gsum8(fmaf(p.dt, cl_s, seed));
        s.p00 = np00; s.p01 = np01; s.p02 = np02;
        s.p11 = np11; s.p12 = np12; s.p22 = np22;
    }
}

__device__ __forceinline__ void fc_out(int lr, float* __restrict__ ys,
                                       float* __restrict__ yvs, int j,
                                       const KS& s, float Rw) {
    if (lr == 0) {
        ys[j]  = s.x + s.n;
        yvs[j] = s.p00 + 2.f * s.p02 + s.p22 + Rw;
    }
}

__global__ __launch_bounds__(256, 1) void kf_kernel(
    const float* __restrict__ v_hist,
    const float* __restrict__ dt_hist,
    const float* __restrict__ x_obs,
    const float* __restrict__ v_fut,
    const float* __restrict__ dt_fut,
    const float* __restrict__ p_log_tau_n,
    const float* __restrict__ p_log_q_n,
    const float* __restrict__ p_log_R_white,
    const float* __restrict__ p_log_P0_nn,
    const float* __restrict__ p_log_p0_xx,
    const float* __restrict__ p_log_p0_uu,
    const float* __restrict__ p_alpha,
    const float* __restrict__ p_c,
    const float* __restrict__ p_kappa,
    const float* __restrict__ p_vc,
    const float* __restrict__ p_qx,
    const float* __restrict__ p_qu,
    const float* __restrict__ p_q_scale,
    const float* __restrict__ W1,
    const float* __restrict__ b1,
    const float* __restrict__ W2,
    const float* __restrict__ b2,
    float* __restrict__ out)
{
    int tid  = blockIdx.x * blockDim.x + threadIdx.x;
    int elem = tid >> 3;
    int lr   = tid & 7;

    Consts C;
    C.expc.x = -p_alpha[0];
    C.expc.y = -expf(-p_log_tau_n[0]);   // -1/tau_n
    C.kappa = p_kappa[0];
    C.c     = p_c[0];
    { float vc = p_vc[0]; C.vc2 = vc * vc; }
    { float qs = p_q_scale[0]; C.qxs = qs * p_qx[0]; C.qus = qs * p_qu[0]; }
    C.qn = expf(p_log_q_n[0]);
    C.Rw = expf(p_log_R_white[0]);
    C.b28 = b2[0] * 0.125f;
    float p0xx = expf(p_log_p0_xx[0]);
    float p0uu = expf(p_log_p0_uu[0]);
    float P0nn = expf(p_log_P0_nn[0]);

    int j0 = lr * 4;
    Wgt w;
    w.wu0.x = W1[j0+0];    w.wu0.y = W1[j0+1];
    w.wu1.x = W1[j0+2];    w.wu1.y = W1[j0+3];
    w.wv0.x = W1[32+j0+0]; w.wv0.y = W1[32+j0+1];
    w.wv1.x = W1[32+j0+2]; w.wv1.y = W1[32+j0+3];
    w.wd0.x = W1[64+j0+0]; w.wd0.y = W1[64+j0+1];
    w.wd1.x = W1[64+j0+2]; w.wd1.y = W1[64+j0+3];
    w.wb0.x = b1[j0+0];    w.wb0.y = b1[j0+1];
    w.wb1.x = b1[j0+2];    w.wb1.y = b1[j0+3];
    w.wn0.x = W2[j0+0];    w.wn0.y = W2[j0+1];
    w.wn1.x = W2[j0+2];    w.wn1.y = W2[j0+3];

    const float* vh = v_hist  + (size_t)elem * L_HIST;
    const float* dh = dt_hist + (size_t)elem * L_HIST;
    const float* oh = x_obs   + (size_t)elem * L_HIST;

    float4 v0c = *(const float4*)(vh);
    float4 d0c = *(const float4*)(dh);
    float4 o0c = *(const float4*)(oh);
    float4 vC  = *(const float4*)(vh + 4);
    float4 dC  = *(const float4*)(dh + 4);
    float4 oC  = *(const float4*)(oh + 4);

    KS s;
    s.x = o0c.x; s.u = 0.f; s.n = 0.f;
    s.p00 = p0xx; s.p11 = p0uu; s.p22 = P0nn;
    s.p01 = 0.f; s.p02 = 0.f; s.p12 = 0.f;

    {   // steps 1..3
        Pre p1 = mkpre(C, w, d0c.y, v0c.x, 0.f);
        Pre p2 = mkpre(C, w, d0c.z, v0c.y, v0c.y - v0c.x);
        Pre p3 = mkpre(C, w, d0c.w, v0c.z, v0c.z - v0c.y);
        kcore<true>(C, w, p1, o0c.y, s);
        kcore<true>(C, w, p2, o0c.z, s);
        kcore<true>(C, w, p3, o0c.w, s);
    }
    float vm2 = v0c.z, vm1 = v0c.w;

    for (int cch = 1; cch < 127; ++cch) {
        int kb = cch * 4;
        float4 vN = *(const float4*)(vh + kb + 4);
        float4 dN = *(const float4*)(dh + kb + 4);
        float4 oN = *(const float4*)(oh + kb + 4);
        Pre pa = mkpre(C, w, dC.x, vm1,  vm1 - vm2);
        Pre pb = mkpre(C, w, dC.y, vC.x, vC.x - vm1);
        Pre pc = mkpre(C, w, dC.z, vC.y, vC.y - vC.x);
        Pre pd = mkpre(C, w, dC.w, vC.z, vC.z - vC.y);
        kcore<true>(C, w, pa, oC.x, s);
        kcore<true>(C, w, pb, oC.y, s);
        kcore<true>(C, w, pc, oC.z, s);
        kcore<true>(C, w, pd, oC.w, s);
        vm2 = vC.z; vm1 = vC.w;
        vC = vN; dC = dN; oC = oN;
    }

    const float* vf = v_fut  + (size_t)elem * HF;
    const float* df = dt_fut + (size_t)elem * HF;
    float4 vFc = *(const float4*)(vf);
    float4 dFc = *(const float4*)(df);

    {   // final filter chunk (steps 508..511)
        Pre pa = mkpre(C, w, dC.x, vm1,  vm1 - vm2);
        Pre pb = mkpre(C, w, dC.y, vC.x, vC.x - vm1);
        Pre pc = mkpre(C, w, dC.z, vC.y, vC.y - vC.x);
        Pre pd = mkpre(C, w, dC.w, vC.z, vC.z - vC.y);
        kcore<true>(C, w, pa, oC.x, s);
        kcore<true>(C, w, pb, oC.y, s);
        kcore<true>(C, w, pc, oC.z, s);
        kcore<true>(C, w, pd, oC.w, s);
    }
    float vprev = vC.w;

    float* ys  = out + (size_t)elem * HF;
    float* yvs = out + (size_t)B_TOT * HF + (size_t)elem * HF;

    for (int f = 0; f < 15; ++f) {
        int jb = f * 4;
        float4 vN = *(const float4*)(vf + jb + 4);
        float4 dN = *(const float4*)(df + jb + 4);
        Pre pa = mkpre(C, w, dFc.x, vFc.x, vFc.x - vprev);
        Pre pb = mkpre(C, w, dFc.y, vFc.y, vFc.y - vFc.x);
        Pre pc = mkpre(C, w, dFc.z, vFc.z, vFc.z - vFc.y);
        Pre pd = mkpre(C, w, dFc.w, vFc.w, vFc.w - vFc.z);
        kcore<false>(C, w, pa, 0.f, s);
        fc_out(lr, ys, yvs, jb + 0, s, C.Rw);
        kcore<false>(C, w, pb, 0.f, s);
        fc_out(lr, ys, yvs, jb + 1, s, C.Rw);
        kcore<false>(C, w, pc, 0.f, s);
        fc_out(lr, ys, yvs, jb + 2, s, C.Rw);
        kcore<false>(C, w, pd, 0.f, s);
        fc_out(lr, ys, yvs, jb + 3, s, C.Rw);
        vprev = vFc.w;
        vFc = vN; dFc = dN;
    }
    {
        Pre pa = mkpre(C, w, dFc.x, vFc.x, vFc.x - vprev);
        Pre pb = mkpre(C, w, dFc.y, vFc.y, vFc.y - vFc.x);
        Pre pc = mkpre(C, w, dFc.z, vFc.z, vFc.z - vFc.y);
        Pre pd = mkpre(C, w, dFc.w, vFc.w, vFc.w - vFc.z);
        kcore<false>(C, w, pa, 0.f, s);
        fc_out(lr, ys, yvs, 60, s, C.Rw);
        kcore<false>(C, w, pb, 0.f, s);
        fc_out(lr, ys, yvs, 61, s, C.Rw);
        kcore<false>(C, w, pc, 0.f, s);
        fc_out(lr, ys, yvs, 62, s, C.Rw);
        kcore<false>(C, w, pd, 0.f, s);
        fc_out(lr, ys, yvs, 63, s, C.Rw);
    }

    if (lr == 0) {
        out[(size_t)2 * B_TOT * HF + elem] = s.u;
    }
}

extern "C" void kernel_launch(void* const* d_in, const int* in_sizes, int n_in,
                              void* d_out, int out_size, void* d_ws, size_t ws_size,
                              hipStream_t stream) {
    const float* v_hist  = (const float*)d_in[0];
    const float* dt_hist = (const float*)d_in[1];
    const float* x_obs   = (const float*)d_in[2];
    const float* v_fut   = (const float*)d_in[3];
    const float* dt_fut  = (const float*)d_in[4];
    const float* log_tau_n   = (const float*)d_in[5];
    const float* log_q_n     = (const float*)d_in[6];
    const float* log_R_white = (const float*)d_in[7];
    const float* log_P0_nn   = (const float*)d_in[8];
    const float* log_p0_xx   = (const float*)d_in[9];
    const float* log_p0_uu   = (const float*)d_in[10];
    const float* alpha   = (const float*)d_in[11];
    const float* c       = (const float*)d_in[12];
    const float* kappa   = (const float*)d_in[13];
    const float* vc      = (const float*)d_in[14];
    const float* qx      = (const float*)d_in[15];
    const float* qu      = (const float*)d_in[16];
    const float* q_scale = (const float*)d_in[17];
    const float* W1 = (const float*)d_in[18];
    const float* b1 = (const float*)d_in[19];
    const float* W2 = (const float*)d_in[20];
    const float* b2 = (const float*)d_in[21];
    float* out = (float*)d_out;

    dim3 block(256);
    dim3 grid((B_TOT * 8) / 256);   // 65536 threads = 1024 waves = 1/SIMD
    kf_kernel<<<grid, block, 0, stream>>>(
        v_hist, dt_hist, x_obs, v_fut, dt_fut,
        log_tau_n, log_q_n, log_R_white, log_P0_nn, log_p0_xx, log_p0_uu,
        alpha, c, kappa, vc, qx, qu, q_scale,
        W1, b1, W2, b2, out);
}